// Round 1
// 116.962 us; speedup vs baseline: 1.0585x; 1.0585x over previous
//
#include <hip/hip_runtime.h>
#include <math.h>

typedef _Float16 half8 __attribute__((ext_vector_type(8)));
typedef _Float16 half4v __attribute__((ext_vector_type(4)));
typedef float floatx4 __attribute__((ext_vector_type(4)));

union U16 { uint4 u; half8 h; };

// ---------------------------------------------------------------------------
// prep1: 517 blocks x 256 thr. No atomics; K-split partials to ws.
//  [0,256):   R partials: dg=bid>>3 (8 d-rows), kq=bid&7 (K=128)
//             Rp[kq][(d0+dl)*256+h] = table-slice @ Wh-slice
//  [256,512): a/bv partials: rg=(bid-256)>>2 (8 rows), kq=(bid-256)&3 (K=64)
//  [512,516): WmT2 pack granules (f16)
//  [516]:     WoPk pack granules (f16)
// ---------------------------------------------------------------------------
__global__ __launch_bounds__(256) void k_prep1(
    const float* __restrict__ hs, const float* __restrict__ Wh,
    const float* __restrict__ Wo,
    float* __restrict__ Rp, float* __restrict__ ap, float* __restrict__ bp,
    uint4* __restrict__ WmT2, uint4* __restrict__ WoPk)
{
  __shared__ __align__(16) char pool[32768];
  int bid = blockIdx.x, tid = threadIdx.x;

  if (bid < 256) {                       // ---- R partials ----
    float (*tbl)[8] = (float(*)[8])pool; // [128 k][8 d]
    int dg = bid >> 3, kq = bid & 7, d0 = dg * 8, k0 = kq * 128;
    for (int idx = tid; idx < 1024; idx += 256) {
      int t = idx >> 3, dl = idx & 7;
      int k = k0 + t;
      float e = (float)(k & ~1) * (1.0f / 1024.f);
      float div = powf(10000.f, e);
      float ang = (float)(d0 + dl) / div;
      tbl[t][dl] = (k & 1) ? cosf(ang) : sinf(ang);
    }
    __syncthreads();
    int h = tid;
    float acc[8] = {0, 0, 0, 0, 0, 0, 0, 0};
    for (int kk = 0; kk < 128; ++kk) {
      float wv = Wh[(k0 + kk) * 256 + h];
      float tr[8];
      *(float4*)&tr[0] = *(const float4*)&tbl[kk][0];
      *(float4*)&tr[4] = *(const float4*)&tbl[kk][4];
#pragma unroll
      for (int dl = 0; dl < 8; ++dl) acc[dl] = fmaf(tr[dl], wv, acc[dl]);
    }
#pragma unroll
    for (int dl = 0; dl < 8; ++dl)
      Rp[kq * 65536 + (d0 + dl) * 256 + h] = acc[dl];  // d=255 row unused

  } else if (bid < 512) {                // ---- a / bv partials ----
    float (*xs)[8] = (float(*)[8])pool;  // [64 k][8 r]
    int g = bid - 256, rg = g >> 2, kq = g & 3;
    int r0 = rg * 8, k0 = kq * 64;
    for (int idx = tid; idx < 512; idx += 256) {
      int kk = idx >> 3, r = idx & 7;
      xs[kk][r] = hs[(r0 + r) * 256 + k0 + kk];
    }
    __syncthreads();
    int h = tid;
    float aa[8] = {0, 0, 0, 0, 0, 0, 0, 0}, bb[8] = {0, 0, 0, 0, 0, 0, 0, 0};
    for (int kk = 0; kk < 64; ++kk) {
      int k = k0 + kk;
      float we = Wh[k * 256 + h];
      float wsv = Wh[(256 + k) * 256 + h];
      float wd = Wh[(512 + k) * 256 + h];
      float wA = we + wd, wB = wsv - wd;
      float xr[8];
      *(float4*)&xr[0] = *(const float4*)&xs[kk][0];
      *(float4*)&xr[4] = *(const float4*)&xs[kk][4];
#pragma unroll
      for (int r = 0; r < 8; ++r) {
        aa[r] = fmaf(xr[r], wA, aa[r]);
        bb[r] = fmaf(xr[r], wB, bb[r]);
      }
    }
#pragma unroll
    for (int r = 0; r < 8; ++r) {
      ap[kq * 131072 + (r0 + r) * 256 + h] = aa[r];
      bp[kq * 131072 + (r0 + r) * 256 + h] = bb[r];
    }

  } else if (bid < 516) {                // ---- WmT2 pack ----
    _Float16 (*T)[256] = (_Float16(*)[256])pool; // [64 k][256 h]
    int q = bid - 512;
    for (int idx = tid; idx < 16384; idx += 256) {
      int k = idx >> 8, h = idx & 255;
      T[k][h] = (_Float16)Wh[(768 + q * 64 + k) * 256 + h];
    }
    __syncthreads();
    for (int gi = tid; gi < 2048; gi += 256) {
      int kbl = gi >> 8, h = gi & 255;
      U16 v;
#pragma unroll
      for (int e = 0; e < 8; ++e) v.h[e] = T[kbl * 8 + e][h];
      WmT2[(q * 8 + kbl) * 256 + h] = v.u;
    }

  } else {                               // ---- WoPk pack ----
    for (int gi = tid; gi < 512; gi += 256) {
      int kb = gi >> 4, c = gi & 15;
      U16 v;
#pragma unroll
      for (int e = 0; e < 8; ++e)
        v.h[e] = (c < 5) ? (_Float16)Wo[(kb * 8 + e) * 5 + c] : (_Float16)0.f;
      WoPk[gi] = v.u;
    }
  }
}

// ---------------------------------------------------------------------------
// prep2: 511 blocks x 256 thr — reduce the K-split partials.
//  [0,255):   R[d][h]  = sum_{kq<8} Rp
//  [255,511): rows 2*(bid-255)+{0,1}: a = sum_{kq<4} ap ; bv = sum bp
// ---------------------------------------------------------------------------
__global__ __launch_bounds__(256) void k_prep2(
    const float* __restrict__ Rp, const float* __restrict__ ap,
    const float* __restrict__ bp,
    float* __restrict__ R, float* __restrict__ a, float* __restrict__ bv)
{
  int bid = blockIdx.x, h = threadIdx.x;
  if (bid < 255) {
    int d = bid;
    float s = 0.f;
#pragma unroll
    for (int kq = 0; kq < 8; ++kq) s += Rp[kq * 65536 + d * 256 + h];
    R[d * 256 + h] = s;
  } else {
    int r0 = (bid - 255) * 2;
#pragma unroll
    for (int rr = 0; rr < 2; ++rr) {
      int r = r0 + rr;
      float sa = 0.f, sb = 0.f;
#pragma unroll
      for (int kq = 0; kq < 4; ++kq) {
        sa += ap[kq * 131072 + r * 256 + h];
        sb += bp[kq * 131072 + r * 256 + h];
      }
      a[r * 256 + h] = sa;
      bv[r * 256 + h] = sb;
    }
  }
}

// ---------------------------------------------------------------------------
// main: 2048 blocks = (b, i, j-tile 64); 4 waves, wave w owns h' [64w,64w+64)
// over all 64 j. acc init = a_i + Wh_b + bv_j + R_d. K-loop barrier-free
// (B-frags from L2, amortized over 4 j-subtiles). Epilogue: tanh -> f16 P in
// As -> ALL 4 waves do the 16j x 16c x K=256 Wo GEMM, float4 stores.
// ---------------------------------------------------------------------------
__global__ __launch_bounds__(256, 4) void k_main(
    const float* __restrict__ hs, const int* __restrict__ mask,
    const float* __restrict__ R, const float* __restrict__ a,
    const float* __restrict__ bvec, const float* __restrict__ Whb,
    const uint4* __restrict__ WmT2, const uint4* __restrict__ WoPk,
    const float* __restrict__ Wob, float* __restrict__ out)
{
  __shared__ __align__(16) _Float16 As[64][264];  // 33.8 KB, +8 pad

  int bid = blockIdx.x, tid = threadIdx.x;
  int jt = bid & 3, i = (bid >> 2) & 255, b = bid >> 10;
  int j0 = jt * 64;
  int lane = tid & 63, w = tid >> 6;
  int c16 = lane & 15, quad = lane >> 4;
  const float* hsb = hs + (size_t)b * 65536;

  // ---- acc init: a_i + bias + bv_j + R_d ----
  float av[4];
#pragma unroll
  for (int ht2 = 0; ht2 < 4; ++ht2) {
    int hp = 64 * w + 16 * ht2 + c16;
    av[ht2] = a[((size_t)(b * 256 + i)) * 256 + hp] + Whb[hp];
  }
  floatx4 acc[4][4];
#pragma unroll
  for (int jt2 = 0; jt2 < 4; ++jt2) {
#pragma unroll
    for (int r = 0; r < 4; ++r) {
      int jl = jt2 * 16 + quad * 4 + r;
      int jg = j0 + jl;
      int dd = jg - i;
      dd = dd < -127 ? -127 : (dd > 127 ? 127 : dd);
      dd += 127;
      const float* bpr = bvec + ((size_t)(b * 256 + jg)) * 256;
      const float* rpr = R + (size_t)dd * 256;
#pragma unroll
      for (int ht2 = 0; ht2 < 4; ++ht2) {
        int hp = 64 * w + 16 * ht2 + c16;
        acc[jt2][ht2][r] = av[ht2] + bpr[hp] + rpr[hp];
      }
    }
  }

  // ---- A tile: As[j][k] = f16(x_i[k] * x_j[k]), 16B granules ----
  {
    int k8 = (tid & 31) * 8;
    float4 xi0 = *(const float4*)(hsb + i * 256 + k8);
    float4 xi1 = *(const float4*)(hsb + i * 256 + k8 + 4);
    int j = tid >> 5;  // 0..7
#pragma unroll
    for (int s = 0; s < 8; ++s, j += 8) {
      float4 xj0 = *(const float4*)(hsb + (j0 + j) * 256 + k8);
      float4 xj1 = *(const float4*)(hsb + (j0 + j) * 256 + k8 + 4);
      half8 p = {(_Float16)(xi0.x * xj0.x), (_Float16)(xi0.y * xj0.y),
                 (_Float16)(xi0.z * xj0.z), (_Float16)(xi0.w * xj0.w),
                 (_Float16)(xi1.x * xj1.x), (_Float16)(xi1.y * xj1.y),
                 (_Float16)(xi1.z * xj1.z), (_Float16)(xi1.w * xj1.w)};
      *(half8*)(&As[j][k8]) = p;
    }
  }
  __syncthreads();

  // ---- K loop (barrier-free): A-frags from LDS, B-frags from L2 ----
#pragma unroll 1
  for (int kc = 0; kc < 4; ++kc) {
#pragma unroll
    for (int ks = 0; ks < 2; ++ks) {
      int kb = kc * 8 + ks * 4 + quad;
      U16 bg[4];
#pragma unroll
      for (int ht2 = 0; ht2 < 4; ++ht2)
        bg[ht2].u = WmT2[kb * 256 + 64 * w + 16 * ht2 + c16];
      half8 af[4];
#pragma unroll
      for (int jt2 = 0; jt2 < 4; ++jt2)
        af[jt2] = *(const half8*)(&As[jt2 * 16 + c16][kc * 64 + ks * 32 + quad * 8]);
#pragma unroll
      for (int jt2 = 0; jt2 < 4; ++jt2)
#pragma unroll
        for (int ht2 = 0; ht2 < 4; ++ht2)
          acc[jt2][ht2] = __builtin_amdgcn_mfma_f32_16x16x32_f16(
              af[jt2], bg[ht2].h, acc[jt2][ht2], 0, 0, 0);
    }
  }

  __syncthreads();  // all A-frag reads done before P overwrites As

  // ---- P = tanh(acc) -> f16 into As ----
#pragma unroll
  for (int jt2 = 0; jt2 < 4; ++jt2) {
#pragma unroll
    for (int ht2 = 0; ht2 < 4; ++ht2) {
      int hp = 64 * w + 16 * ht2 + c16;
#pragma unroll
      for (int r = 0; r < 4; ++r) {
        int jl = jt2 * 16 + quad * 4 + r;
        float x = acc[jt2][ht2][r];
        float t = 1.f - 2.f / (__expf(2.f * x) + 1.f);  // tanh, inf-safe
        As[jl][hp] = (_Float16)t;
      }
    }
  }
  __syncthreads();

  // ---- epilogue GEMM (all 4 waves): rows [16w,16w+16) x 16c, K=256 ----
  {
    U16 wog[8];
#pragma unroll
    for (int s = 0; s < 8; ++s) wog[s].u = WoPk[(s * 4 + quad) * 16 + c16];
    floatx4 accE = {0.f, 0.f, 0.f, 0.f};
#pragma unroll
    for (int s = 0; s < 8; ++s) {
      half8 ae = *(const half8*)(&As[16 * w + c16][s * 32 + quad * 8]);
      accE = __builtin_amdgcn_mfma_f32_16x16x32_f16(ae, wog[s].h, accE, 0, 0, 0);
    }
    const int* mb = mask + b * 256;
    int mi = mb[i];
    int jg0 = j0 + 16 * w + quad * 4;
    int mj[4];
    *(int4*)mj = *(const int4*)(mb + jg0);
    float wob = (c16 < 5) ? Wob[c16] : 0.f;
    float4 v;
#pragma unroll
    for (int r = 0; r < 4; ++r) {
      int jg = jg0 + r;
      float x = accE[r] + wob;
      if (!(mi && mj[r])) x = -INFINITY;
      if (jg < i) x -= 1e12f;
      ((float*)&v)[r] = x;
    }
    if (c16 < 5)
      *(float4*)(&out[(((size_t)b * 5 + c16) * 256 + i) * 256 + jg0]) = v;
  }
}

extern "C" void kernel_launch(void* const* d_in, const int* in_sizes, int n_in,
                              void* d_out, int out_size, void* d_ws, size_t ws_size,
                              hipStream_t stream) {
  const float* hs   = (const float*)d_in[0];
  const int*   mask = (const int*)d_in[1];
  const float* Wh_w = (const float*)d_in[2];
  const float* Wh_b = (const float*)d_in[3];
  const float* Wo_w = (const float*)d_in[4];
  const float* Wo_b = (const float*)d_in[5];

  char* ws = (char*)d_ws;
  float* R    = (float*)(ws + 0);        //  256*256*4  = 262144
  float* a    = (float*)(ws + 262144);   //  512*256*4  = 524288
  float* bv   = (float*)(ws + 786432);   //  512*256*4  = 524288
  uint4* WmT2 = (uint4*)(ws + 1310720);  //  256*256*2  = 131072
  uint4* WoPk = (uint4*)(ws + 1441792);  //  512*16     =   8192
  float* Rp   = (float*)(ws + 1449984);  // 8*65536*4   = 2097152
  float* ap   = (float*)(ws + 3547136);  // 4*131072*4  = 2097152
  float* bp   = (float*)(ws + 5644288);  // 4*131072*4  = 2097152  (end ~7.4MB)

  k_prep1<<<517, 256, 0, stream>>>(hs, Wh_w, Wo_w, Rp, ap, bp, WmT2, WoPk);
  k_prep2<<<511, 256, 0, stream>>>(Rp, ap, bp, R, a, bv);
  k_main<<<2048, 256, 0, stream>>>(hs, mask, R, a, bv, Wh_b, WmT2, WoPk, Wo_b,
                                   (float*)d_out);
}

// Round 2
// 110.842 us; speedup vs baseline: 1.1169x; 1.0552x over previous
//
#include <hip/hip_runtime.h>
#include <math.h>

typedef _Float16 half8 __attribute__((ext_vector_type(8)));
typedef _Float16 half4v __attribute__((ext_vector_type(4)));
typedef float floatx4 __attribute__((ext_vector_type(4)));

union U16 { uint4 u; half8 h; };

// ---------------------------------------------------------------------------
// prep1: 517 blocks x 256 thr. No atomics; K-split partials to ws.
//  [0,256):   R partials: dg=bid>>3 (8 d-rows), kq=bid&7 (K=128)
//             Rp[kq][(d0+dl)*256+h] = table-slice @ Wh-slice
//  [256,512): a/bv partials: rg=(bid-256)>>2 (8 rows), kq=(bid-256)&3 (K=64)
//  [512,516): WmT2 pack granules (f16)
//  [516]:     WoPk pack granules (f16)
// ---------------------------------------------------------------------------
__global__ __launch_bounds__(256) void k_prep1(
    const float* __restrict__ hs, const float* __restrict__ Wh,
    const float* __restrict__ Wo,
    float* __restrict__ Rp, float* __restrict__ ap, float* __restrict__ bp,
    uint4* __restrict__ WmT2, uint4* __restrict__ WoPk)
{
  __shared__ __align__(16) char pool[32768];
  int bid = blockIdx.x, tid = threadIdx.x;

  if (bid < 256) {                       // ---- R partials ----
    float (*tbl)[8] = (float(*)[8])pool; // [128 k][8 d]
    int dg = bid >> 3, kq = bid & 7, d0 = dg * 8, k0 = kq * 128;
    for (int idx = tid; idx < 1024; idx += 256) {
      int t = idx >> 3, dl = idx & 7;
      int k = k0 + t;
      float e = (float)(k & ~1) * (1.0f / 1024.f);
      float div = powf(10000.f, e);
      float ang = (float)(d0 + dl) / div;
      tbl[t][dl] = (k & 1) ? cosf(ang) : sinf(ang);
    }
    __syncthreads();
    int h = tid;
    float acc[8] = {0, 0, 0, 0, 0, 0, 0, 0};
    for (int kk = 0; kk < 128; ++kk) {
      float wv = Wh[(k0 + kk) * 256 + h];
      float tr[8];
      *(float4*)&tr[0] = *(const float4*)&tbl[kk][0];
      *(float4*)&tr[4] = *(const float4*)&tbl[kk][4];
#pragma unroll
      for (int dl = 0; dl < 8; ++dl) acc[dl] = fmaf(tr[dl], wv, acc[dl]);
    }
#pragma unroll
    for (int dl = 0; dl < 8; ++dl)
      Rp[kq * 65536 + (d0 + dl) * 256 + h] = acc[dl];  // d=255 row unused

  } else if (bid < 512) {                // ---- a / bv partials ----
    float (*xs)[8] = (float(*)[8])pool;  // [64 k][8 r]
    int g = bid - 256, rg = g >> 2, kq = g & 3;
    int r0 = rg * 8, k0 = kq * 64;
    for (int idx = tid; idx < 512; idx += 256) {
      int kk = idx >> 3, r = idx & 7;
      xs[kk][r] = hs[(r0 + r) * 256 + k0 + kk];
    }
    __syncthreads();
    int h = tid;
    float aa[8] = {0, 0, 0, 0, 0, 0, 0, 0}, bb[8] = {0, 0, 0, 0, 0, 0, 0, 0};
    for (int kk = 0; kk < 64; ++kk) {
      int k = k0 + kk;
      float we = Wh[k * 256 + h];
      float wsv = Wh[(256 + k) * 256 + h];
      float wd = Wh[(512 + k) * 256 + h];
      float wA = we + wd, wB = wsv - wd;
      float xr[8];
      *(float4*)&xr[0] = *(const float4*)&xs[kk][0];
      *(float4*)&xr[4] = *(const float4*)&xs[kk][4];
#pragma unroll
      for (int r = 0; r < 8; ++r) {
        aa[r] = fmaf(xr[r], wA, aa[r]);
        bb[r] = fmaf(xr[r], wB, bb[r]);
      }
    }
#pragma unroll
    for (int r = 0; r < 8; ++r) {
      ap[kq * 131072 + (r0 + r) * 256 + h] = aa[r];
      bp[kq * 131072 + (r0 + r) * 256 + h] = bb[r];
    }

  } else if (bid < 516) {                // ---- WmT2 pack ----
    _Float16 (*T)[256] = (_Float16(*)[256])pool; // [64 k][256 h]
    int q = bid - 512;
    for (int idx = tid; idx < 16384; idx += 256) {
      int k = idx >> 8, h = idx & 255;
      T[k][h] = (_Float16)Wh[(768 + q * 64 + k) * 256 + h];
    }
    __syncthreads();
    for (int gi = tid; gi < 2048; gi += 256) {
      int kbl = gi >> 8, h = gi & 255;
      U16 v;
#pragma unroll
      for (int e = 0; e < 8; ++e) v.h[e] = T[kbl * 8 + e][h];
      WmT2[(q * 8 + kbl) * 256 + h] = v.u;
    }

  } else {                               // ---- WoPk pack ----
    for (int gi = tid; gi < 512; gi += 256) {
      int kb = gi >> 4, c = gi & 15;
      U16 v;
#pragma unroll
      for (int e = 0; e < 8; ++e)
        v.h[e] = (c < 5) ? (_Float16)Wo[(kb * 8 + e) * 5 + c] : (_Float16)0.f;
      WoPk[gi] = v.u;
    }
  }
}

// ---------------------------------------------------------------------------
// prep2: 511 blocks x 256 thr — reduce the K-split partials.
//  [0,255):   R[d][h]  = sum_{kq<8} Rp
//  [255,511): rows 2*(bid-255)+{0,1}: a = sum_{kq<4} ap ; bv = sum bp
// ---------------------------------------------------------------------------
__global__ __launch_bounds__(256) void k_prep2(
    const float* __restrict__ Rp, const float* __restrict__ ap,
    const float* __restrict__ bp,
    float* __restrict__ R, float* __restrict__ a, float* __restrict__ bv)
{
  int bid = blockIdx.x, h = threadIdx.x;
  if (bid < 255) {
    int d = bid;
    float s = 0.f;
#pragma unroll
    for (int kq = 0; kq < 8; ++kq) s += Rp[kq * 65536 + d * 256 + h];
    R[d * 256 + h] = s;
  } else {
    int r0 = (bid - 255) * 2;
#pragma unroll
    for (int rr = 0; rr < 2; ++rr) {
      int r = r0 + rr;
      float sa = 0.f, sb = 0.f;
#pragma unroll
      for (int kq = 0; kq < 4; ++kq) {
        sa += ap[kq * 131072 + r * 256 + h];
        sb += bp[kq * 131072 + r * 256 + h];
      }
      a[r * 256 + h] = sa;
      bv[r * 256 + h] = sb;
    }
  }
}

// ---------------------------------------------------------------------------
// main: 2048 blocks = (b, i, j-tile 64); 4 waves, wave w owns h' [64w,64w+64)
// over all 64 j. acc init = a_i + Wh_b + (bv_j + R_d) where bv+R is staged
// cooperatively into LDS (float4 reads, 2 halves of 32 rows, stride 268 f32
// -> quads alternate bank halves = conflict-free). K-loop barrier-free
// (B-frags from L2, amortized over 4 j-subtiles). Epilogue: tanh via
// v_rcp (no full-precision div) -> f16 P in As -> all 4 waves do the
// 16j x 16c x K=256 Wo GEMM, float4 stores.
// ---------------------------------------------------------------------------
__global__ __launch_bounds__(256, 4) void k_main(
    const float* __restrict__ hs, const int* __restrict__ mask,
    const float* __restrict__ R, const float* __restrict__ a,
    const float* __restrict__ bvec, const float* __restrict__ Whb,
    const uint4* __restrict__ WmT2, const uint4* __restrict__ WoPk,
    const float* __restrict__ Wob, float* __restrict__ out)
{
  __shared__ __align__(16) char smem[34304];          // max(34304, 33792)
  _Float16 (*As)[264] = (_Float16(*)[264])smem;       // [64][264] f16, 33792 B
  float (*stg)[268] = (float(*)[268])smem;            // [32][268] f32, 34304 B

  int bid = blockIdx.x, tid = threadIdx.x;
  int jt = bid & 3, i = (bid >> 2) & 255, b = bid >> 10;
  int j0 = jt * 64;
  int lane = tid & 63, w = tid >> 6;
  int c16 = lane & 15, quad = lane >> 4;
  const float* hsb = hs + (size_t)b * 65536;

  // ---- per-thread constant part of init: a_i + bias ----
  float av[4];
#pragma unroll
  for (int ht2 = 0; ht2 < 4; ++ht2) {
    int hp = 64 * w + 16 * ht2 + c16;
    av[ht2] = a[((size_t)(b * 256 + i)) * 256 + hp] + Whb[hp];
  }

  // ---- acc init via LDS-staged (bv_j + R_d), two 32-row halves ----
  floatx4 acc[4][4];
#pragma unroll
  for (int hf = 0; hf < 2; ++hf) {
    int jbase = j0 + hf * 32;
    // stage: 32 rows x 256 cols, float4-vectorized, bv+R pre-summed
#pragma unroll
    for (int it = 0; it < 8; ++it) {
      int idx = it * 256 + tid;
      int row = idx >> 6;            // 0..31
      int c4 = (idx & 63) << 2;      // 0..252 step 4
      int jg = jbase + row;
      int dd = jg - i;
      dd = dd < -127 ? -127 : (dd > 127 ? 127 : dd);
      dd += 127;
      float4 bb = *(const float4*)(bvec + ((size_t)(b * 256 + jg)) * 256 + c4);
      float4 rr = *(const float4*)(R + (size_t)dd * 256 + c4);
      float4 s;
      s.x = bb.x + rr.x; s.y = bb.y + rr.y;
      s.z = bb.z + rr.z; s.w = bb.w + rr.w;
      *(float4*)&stg[row][c4] = s;
    }
    __syncthreads();
#pragma unroll
    for (int jj = 0; jj < 2; ++jj) {
      int jt2 = hf * 2 + jj;
#pragma unroll
      for (int r = 0; r < 4; ++r) {
        int jl32 = jj * 16 + quad * 4 + r;
#pragma unroll
        for (int ht2 = 0; ht2 < 4; ++ht2)
          acc[jt2][ht2][r] = av[ht2] + stg[jl32][64 * w + 16 * ht2 + c16];
      }
    }
    __syncthreads();  // stg reads done before next stage / A-tile overwrite
  }

  // ---- A tile: As[j][k] = f16(x_i[k] * x_j[k]), 16B granules ----
  {
    int k8 = (tid & 31) * 8;
    float4 xi0 = *(const float4*)(hsb + i * 256 + k8);
    float4 xi1 = *(const float4*)(hsb + i * 256 + k8 + 4);
    int j = tid >> 5;  // 0..7
#pragma unroll
    for (int s = 0; s < 8; ++s, j += 8) {
      float4 xj0 = *(const float4*)(hsb + (j0 + j) * 256 + k8);
      float4 xj1 = *(const float4*)(hsb + (j0 + j) * 256 + k8 + 4);
      half8 p = {(_Float16)(xi0.x * xj0.x), (_Float16)(xi0.y * xj0.y),
                 (_Float16)(xi0.z * xj0.z), (_Float16)(xi0.w * xj0.w),
                 (_Float16)(xi1.x * xj1.x), (_Float16)(xi1.y * xj1.y),
                 (_Float16)(xi1.z * xj1.z), (_Float16)(xi1.w * xj1.w)};
      *(half8*)(&As[j][k8]) = p;
    }
  }
  __syncthreads();

  // ---- K loop (barrier-free): A-frags from LDS, B-frags from L2 ----
#pragma unroll 1
  for (int kc = 0; kc < 4; ++kc) {
#pragma unroll
    for (int ks = 0; ks < 2; ++ks) {
      int kb = kc * 8 + ks * 4 + quad;
      U16 bg[4];
#pragma unroll
      for (int ht2 = 0; ht2 < 4; ++ht2)
        bg[ht2].u = WmT2[kb * 256 + 64 * w + 16 * ht2 + c16];
      half8 af[4];
#pragma unroll
      for (int jt2 = 0; jt2 < 4; ++jt2)
        af[jt2] = *(const half8*)(&As[jt2 * 16 + c16][kc * 64 + ks * 32 + quad * 8]);
#pragma unroll
      for (int jt2 = 0; jt2 < 4; ++jt2)
#pragma unroll
        for (int ht2 = 0; ht2 < 4; ++ht2)
          acc[jt2][ht2] = __builtin_amdgcn_mfma_f32_16x16x32_f16(
              af[jt2], bg[ht2].h, acc[jt2][ht2], 0, 0, 0);
    }
  }

  __syncthreads();  // all A-frag reads done before P overwrites As

  // ---- P = tanh(acc) -> f16 into As (tanh via v_rcp, no precise div) ----
#pragma unroll
  for (int jt2 = 0; jt2 < 4; ++jt2) {
#pragma unroll
    for (int ht2 = 0; ht2 < 4; ++ht2) {
      int hp = 64 * w + 16 * ht2 + c16;
#pragma unroll
      for (int r = 0; r < 4; ++r) {
        int jl = jt2 * 16 + quad * 4 + r;
        float x = acc[jt2][ht2][r];
        float e = __expf(2.f * x);                       // inf-safe
        float t = fmaf(-2.f, __builtin_amdgcn_rcpf(e + 1.f), 1.f);
        As[jl][hp] = (_Float16)t;
      }
    }
  }
  __syncthreads();

  // ---- epilogue GEMM (all 4 waves): rows [16w,16w+16) x 16c, K=256 ----
  {
    U16 wog[8];
#pragma unroll
    for (int s = 0; s < 8; ++s) wog[s].u = WoPk[(s * 4 + quad) * 16 + c16];
    floatx4 accE = {0.f, 0.f, 0.f, 0.f};
#pragma unroll
    for (int s = 0; s < 8; ++s) {
      half8 ae = *(const half8*)(&As[16 * w + c16][s * 32 + quad * 8]);
      accE = __builtin_amdgcn_mfma_f32_16x16x32_f16(ae, wog[s].h, accE, 0, 0, 0);
    }
    const int* mb = mask + b * 256;
    int mi = mb[i];
    int jg0 = j0 + 16 * w + quad * 4;
    int mj[4];
    *(int4*)mj = *(const int4*)(mb + jg0);
    float wob = (c16 < 5) ? Wob[c16] : 0.f;
    float4 v;
#pragma unroll
    for (int r = 0; r < 4; ++r) {
      int jg = jg0 + r;
      float x = accE[r] + wob;
      if (!(mi && mj[r])) x = -INFINITY;
      if (jg < i) x -= 1e12f;
      ((float*)&v)[r] = x;
    }
    if (c16 < 5)
      *(float4*)(&out[(((size_t)b * 5 + c16) * 256 + i) * 256 + jg0]) = v;
  }
}

extern "C" void kernel_launch(void* const* d_in, const int* in_sizes, int n_in,
                              void* d_out, int out_size, void* d_ws, size_t ws_size,
                              hipStream_t stream) {
  const float* hs   = (const float*)d_in[0];
  const int*   mask = (const int*)d_in[1];
  const float* Wh_w = (const float*)d_in[2];
  const float* Wh_b = (const float*)d_in[3];
  const float* Wo_w = (const float*)d_in[4];
  const float* Wo_b = (const float*)d_in[5];

  char* ws = (char*)d_ws;
  float* R    = (float*)(ws + 0);        //  256*256*4  = 262144
  float* a    = (float*)(ws + 262144);   //  512*256*4  = 524288
  float* bv   = (float*)(ws + 786432);   //  512*256*4  = 524288
  uint4* WmT2 = (uint4*)(ws + 1310720);  //  256*256*2  = 131072
  uint4* WoPk = (uint4*)(ws + 1441792);  //  512*16     =   8192
  float* Rp   = (float*)(ws + 1449984);  // 8*65536*4   = 2097152
  float* ap   = (float*)(ws + 3547136);  // 4*131072*4  = 2097152
  float* bp   = (float*)(ws + 5644288);  // 4*131072*4  = 2097152  (end ~7.4MB)

  k_prep1<<<517, 256, 0, stream>>>(hs, Wh_w, Wo_w, Rp, ap, bp, WmT2, WoPk);
  k_prep2<<<511, 256, 0, stream>>>(Rp, ap, bp, R, a, bv);
  k_main<<<2048, 256, 0, stream>>>(hs, mask, R, a, bv, Wh_b, WmT2, WoPk, Wo_b,
                                   (float*)d_out);
}